// Round 2
// baseline (584.198 us; speedup 1.0000x reference)
//
#include <hip/hip_runtime.h>
#include <stdint.h>

typedef __attribute__((ext_vector_type(8))) short short8;
typedef __attribute__((ext_vector_type(4))) float floatx4;

#define B_DIM 8192
#define K_DIM 2048
#define N_DIM 2048

// round-to-nearest-even fp32 -> bf16
__device__ __forceinline__ unsigned short f2bf(float f) {
    union { float f; unsigned u; } v; v.f = f;
    unsigned r = v.u + 0x7fffu + ((v.u >> 16) & 1u);
    return (unsigned short)(r >> 16);
}

__device__ __forceinline__ void gld_lds16(const void* g, void* l) {
    __builtin_amdgcn_global_load_lds(
        (const __attribute__((address_space(1))) void*)g,
        (__attribute__((address_space(3))) void*)l, 16, 0, 0);
}

// ---------------- prepass 1: X -> Xb (bf16), Lb = bf16(log(|x|+eps)) ----------------
__global__ __launch_bounds__(256) void prep_x(const float4* __restrict__ X4,
                                              ushort* __restrict__ Xb,
                                              ushort* __restrict__ Lb) {
    int i = blockIdx.x * 256 + threadIdx.x;
    float4 v = X4[i];
    ushort4 xb, lb;
    xb.x = f2bf(v.x); xb.y = f2bf(v.y); xb.z = f2bf(v.z); xb.w = f2bf(v.w);
    lb.x = f2bf(__logf(fabsf(v.x) + 1e-7f));
    lb.y = f2bf(__logf(fabsf(v.y) + 1e-7f));
    lb.z = f2bf(__logf(fabsf(v.z) + 1e-7f));
    lb.w = f2bf(__logf(fabsf(v.w) + 1e-7f));
    *(ushort4*)(Xb + (size_t)i * 4) = xb;
    *(ushort4*)(Lb + (size_t)i * 4) = lb;
}

// ---------------- prepass 2: Wt[n][k] = bf16(tanh(Wh)*sigmoid(Mh)), Gt[n][k] = bf16(gate) ----
__global__ __launch_bounds__(256) void prep_wg(const float* __restrict__ Wh,
                                               const float* __restrict__ Mh,
                                               const float* __restrict__ Gf,
                                               ushort* __restrict__ Wt,
                                               ushort* __restrict__ Gt) {
    __shared__ float tw[32][33];
    __shared__ float tg[32][33];
    const int k0 = blockIdx.y * 32, n0 = blockIdx.x * 32;
    const int tx = threadIdx.x, ty = threadIdx.y;  // 32 x 8
#pragma unroll
    for (int i = 0; i < 4; i++) {
        int k = k0 + ty + i * 8;
        int n = n0 + tx;
        size_t idx = (size_t)k * N_DIM + n;
        float wh = Wh[idx], mh = Mh[idx];
        tw[ty + i * 8][tx] = tanhf(wh) * (1.f / (1.f + __expf(-mh)));
        tg[ty + i * 8][tx] = Gf[idx];
    }
    __syncthreads();
#pragma unroll
    for (int i = 0; i < 4; i++) {
        int n = n0 + ty + i * 8;
        int k = k0 + tx;
        Wt[(size_t)n * K_DIM + k] = f2bf(tw[tx][ty + i * 8]);
        Gt[(size_t)n * K_DIM + k] = f2bf(tg[tx][ty + i * 8]);
    }
}

// ---------------- fused GEMM: a = Xb@Wt^T, lm = Lb@Wt^T, gl = Xb@Gt^T ----------------
// out = sigmoid(gl)*a + (1-sigmoid(gl))*exp(lm)
// 128x128 block tile, 4 waves (2x2), 64x64 per wave per acc set, BK=32.
//
// Round-2 changes (vs 287us gemm, MfmaUtil 31% = the 2-phase stall signature, m233):
//  (1) T4 counted-vmcnt pipeline: COMPUTE(cur) -> barrier -> STAGE(cur<-k+64)
//      -> vmcnt(8) -> barrier. The wait for the next buffer's loads has a full
//      compute phase of slack; freshly issued loads stay in flight ACROSS the
//      barrier. Main loop never drains vmcnt(0).
//  (2) T5 s_setprio(1) around each MFMA cluster (structure now role-splits
//      waves: one block stages while the other MFMAs -> T5's prerequisite).
//  (3) T1 XCD remap: each XCD owns a 2-N-column strip so its W/G panels
//      (2 MB) stay L2-resident (FETCH showed B panels re-fetched ~16x).
// Carried from round 1:
//  - T2 XOR bank-swizzle (rule #21: linear gld_lds dest, swizzle-inverse
//    GLOBAL source, XOR on the read address). Bijective.
//  - LDS is ONE shared object (cross-section offsets legal only within one
//    object; the old four-array version read garbage).
#define SEC  (128 * 32)        // elems per section (8 KB)
#define BUFE (4 * SEC)         // elems per buffer  (32 KB)

__global__ __launch_bounds__(256, 2) void gemm_fused(const ushort* __restrict__ Xb,
                                                     const ushort* __restrict__ Lb,
                                                     const ushort* __restrict__ Wt,
                                                     const ushort* __restrict__ Gt,
                                                     float* __restrict__ out) {
    __shared__ ushort smem[2 * BUFE];
    ushort* s0 = smem;
    ushort* s1 = smem + BUFE;

    const int t = threadIdx.x;
    const int lane = t & 63;
    const int w = t >> 6;
    const int wm = w >> 1, wn = w & 1;

    // T1: XCD-aware remap. lin&7 = XCD under round-robin dispatch. Each XCD
    // gets N-columns {2*xcd, 2*xcd+1} and all 64 M-tiles. Bijective:
    // tileN keyed by lin bits 0..3, tileM by bits 4..9 (1024 = 16*64).
    const int lin = blockIdx.x + gridDim.x * blockIdx.y;
    const int tileN = ((lin & 7) << 1) | ((lin >> 3) & 1);
    const int tileM = lin >> 4;
    const int rowA = tileM * 128;   // M tile base
    const int rowB = tileN * 128;   // N tile base

    floatx4 acca[4][4], accm[4][4], accg[4][4];
    const floatx4 z = {0.f, 0.f, 0.f, 0.f};
#pragma unroll
    for (int i = 0; i < 4; i++)
#pragma unroll
        for (int j = 0; j < 4; j++) { acca[i][j] = z; accm[i][j] = z; accg[i][j] = z; }

    // ---- staging: swizzle-inverse source coordinates -------------------------
    // dest byte d (linear, = thread*16) holds global (r,c) with
    // d == (r*64 + c*16) ^ ((r&7)<<4).
    // inverse: r = 2*(d>>7) | ((d>>6)^(d>>8))&1 ; c = ((d>>4)&3) ^ (r&3).
    const int d0 = t * 16;
    const int d1 = (t + 256) * 16;
    const int r0 = ((d0 >> 7) << 1) | (((d0 >> 6) ^ (d0 >> 8)) & 1);
    const int c0 = ((d0 >> 4) & 3) ^ (r0 & 3);
    const int r1 = ((d1 >> 7) << 1) | (((d1 >> 6) ^ (d1 >> 8)) & 1);
    const int c1 = ((d1 >> 4) & 3) ^ (r1 & 3);
    const int ga0 = (rowA + r0) * K_DIM + c0 * 8;
    const int ga1 = (rowA + r1) * K_DIM + c1 * 8;
    const int gb0 = (rowB + r0) * K_DIM + c0 * 8;
    const int gb1 = (rowB + r1) * K_DIM + c1 * 8;
    const int e0 = t * 8, e1 = (t + 256) * 8;   // linear dest (elems)

#define STAGE(sb, k0) do {                                   \
    gld_lds16(Xb + ga0 + (k0), (sb) + e0);                   \
    gld_lds16(Xb + ga1 + (k0), (sb) + e1);                   \
    gld_lds16(Lb + ga0 + (k0), (sb) + SEC + e0);             \
    gld_lds16(Lb + ga1 + (k0), (sb) + SEC + e1);             \
    gld_lds16(Wt + gb0 + (k0), (sb) + 2 * SEC + e0);         \
    gld_lds16(Wt + gb1 + (k0), (sb) + 2 * SEC + e1);         \
    gld_lds16(Gt + gb0 + (k0), (sb) + 3 * SEC + e0);         \
    gld_lds16(Gt + gb1 + (k0), (sb) + 3 * SEC + e1);         \
} while (0)

    // ---- fragment read bases (byte offsets, swizzled) ------------------------
    const int lr = lane & 15;
    const int rbA = (((wm * 64 + lr) * 64) + ((lane >> 4) * 16)) ^ ((lr & 7) << 4);
    const int rbB = (((wn * 64 + lr) * 64) + ((lane >> 4) * 16)) ^ ((lr & 7) << 4);
    // per-mi/ni offsets are +mi*1024B (16 rows) — bits >=10, no swizzle overlap;
    // cross-section offset +SEC*2 bytes likewise.

#define COMPUTE(sb) do {                                                        \
    const char* bA = (const char*)(sb) + rbA;                                   \
    const char* bB = (const char*)(sb) + 2 * SEC * 2 + rbB;                     \
    short8 bw[4], bg[4];                                                        \
    _Pragma("unroll")                                                           \
    for (int ni = 0; ni < 4; ni++) {                                            \
        bw[ni] = *(const short8*)(bB + ni * 1024);                              \
        bg[ni] = *(const short8*)(bB + SEC * 2 + ni * 1024);                    \
    }                                                                           \
    _Pragma("unroll")                                                           \
    for (int mi = 0; mi < 4; mi++) {                                            \
        short8 ax = *(const short8*)(bA + mi * 1024);                           \
        short8 al = *(const short8*)(bA + SEC * 2 + mi * 1024);                 \
        __builtin_amdgcn_s_setprio(1);                                          \
        _Pragma("unroll")                                                       \
        for (int ni = 0; ni < 4; ni++) {                                        \
            acca[mi][ni] = __builtin_amdgcn_mfma_f32_16x16x32_bf16(ax, bw[ni], acca[mi][ni], 0, 0, 0); \
            accm[mi][ni] = __builtin_amdgcn_mfma_f32_16x16x32_bf16(al, bw[ni], accm[mi][ni], 0, 0, 0); \
            accg[mi][ni] = __builtin_amdgcn_mfma_f32_16x16x32_bf16(ax, bg[ni], accg[mi][ni], 0, 0, 0); \
        }                                                                       \
        __builtin_amdgcn_s_setprio(0);                                          \
    }                                                                           \
} while (0)

#define VMCNT8() asm volatile("s_waitcnt vmcnt(8)" ::: "memory")
#define VMCNT0() asm volatile("s_waitcnt vmcnt(0)" ::: "memory")

    // prologue: fill both buffers, wait only for buffer 0 (8 stay in flight)
    STAGE(s0, 0);
    STAGE(s1, 32);
    VMCNT8();
    __syncthreads();

    for (int k0 = 0; k0 < K_DIM; k0 += 64) {
        COMPUTE(s0);                       // s0 holds k0
        __syncthreads();                   // all waves done reading s0
        if (k0 + 64 < K_DIM) {
            STAGE(s0, k0 + 64);            // in flight: 8(s1) + 8(s0 new)
            VMCNT8();                      // s1's loads (1 K-step old) landed
        } else {
            VMCNT0();                      // tail: only s1's 8 in flight
        }
        __syncthreads();
        COMPUTE(s1);                       // s1 holds k0+32
        __syncthreads();
        if (k0 + 96 < K_DIM) {
            STAGE(s1, k0 + 96);
            VMCNT8();
            __syncthreads();
        } else if (k0 + 64 < K_DIM) {
            VMCNT0();
            __syncthreads();
        }
    }

    const int rsub = (lane >> 4) << 2;
#pragma unroll
    for (int mi = 0; mi < 4; mi++)
#pragma unroll
        for (int ni = 0; ni < 4; ni++)
#pragma unroll
            for (int r = 0; r < 4; r++) {
                int row = rowA + wm * 64 + mi * 16 + rsub + r;
                int col = rowB + wn * 64 + ni * 16 + lr;
                float g = 1.f / (1.f + __expf(-accg[mi][ni][r]));
                float a = acca[mi][ni][r];
                float m = __expf(accm[mi][ni][r]);
                out[(size_t)row * N_DIM + col] = g * a + (1.f - g) * m;
            }
}

extern "C" void kernel_launch(void* const* d_in, const int* in_sizes, int n_in,
                              void* d_out, int out_size, void* d_ws, size_t ws_size,
                              hipStream_t stream) {
    const float* X  = (const float*)d_in[0];
    const float* Wh = (const float*)d_in[1];
    const float* Mh = (const float*)d_in[2];
    const float* Gf = (const float*)d_in[3];
    float* out = (float*)d_out;

    // workspace layout (bytes):
    //   Xb : B*K*2  = 33,554,432
    //   Lb : B*K*2  = 33,554,432
    //   Wt : N*K*2  =  8,388,608   (transposed: [n][k])
    //   Gt : N*K*2  =  8,388,608
    char* ws = (char*)d_ws;
    ushort* Xb = (ushort*)(ws);
    ushort* Lb = (ushort*)(ws + (size_t)B_DIM * K_DIM * 2);
    ushort* Wt = (ushort*)(ws + (size_t)B_DIM * K_DIM * 4);
    ushort* Gt = (ushort*)(ws + (size_t)B_DIM * K_DIM * 4 + (size_t)N_DIM * K_DIM * 2);

    prep_x<<<dim3((B_DIM * K_DIM) / (256 * 4)), dim3(256), 0, stream>>>(
        (const float4*)X, Xb, Lb);

    prep_wg<<<dim3(N_DIM / 32, K_DIM / 32), dim3(32, 8), 0, stream>>>(Wh, Mh, Gf, Wt, Gt);

    gemm_fused<<<dim3(N_DIM / 128, B_DIM / 128), dim3(256), 0, stream>>>(Xb, Lb, Wt, Gt, out);
}

// Round 3
// 423.875 us; speedup vs baseline: 1.3782x; 1.3782x over previous
//
#include <hip/hip_runtime.h>
#include <stdint.h>

typedef __attribute__((ext_vector_type(8))) short short8;
typedef __attribute__((ext_vector_type(4))) float floatx4;

#define B_DIM 8192
#define K_DIM 2048
#define N_DIM 2048

// round-to-nearest-even fp32 -> bf16
__device__ __forceinline__ unsigned short f2bf(float f) {
    union { float f; unsigned u; } v; v.f = f;
    unsigned r = v.u + 0x7fffu + ((v.u >> 16) & 1u);
    return (unsigned short)(r >> 16);
}

__device__ __forceinline__ void gld_lds16(const void* g, void* l) {
    __builtin_amdgcn_global_load_lds(
        (const __attribute__((address_space(1))) void*)g,
        (__attribute__((address_space(3))) void*)l, 16, 0, 0);
}

// ---------------- prepass 1: X -> Xb (bf16), Lb = bf16(log(|x|+eps)) ----------------
__global__ __launch_bounds__(256) void prep_x(const float4* __restrict__ X4,
                                              ushort* __restrict__ Xb,
                                              ushort* __restrict__ Lb) {
    int i = blockIdx.x * 256 + threadIdx.x;
    float4 v = X4[i];
    ushort4 xb, lb;
    xb.x = f2bf(v.x); xb.y = f2bf(v.y); xb.z = f2bf(v.z); xb.w = f2bf(v.w);
    lb.x = f2bf(__logf(fabsf(v.x) + 1e-7f));
    lb.y = f2bf(__logf(fabsf(v.y) + 1e-7f));
    lb.z = f2bf(__logf(fabsf(v.z) + 1e-7f));
    lb.w = f2bf(__logf(fabsf(v.w) + 1e-7f));
    *(ushort4*)(Xb + (size_t)i * 4) = xb;
    *(ushort4*)(Lb + (size_t)i * 4) = lb;
}

// ---------------- prepass 2: Wt[n][k] = bf16(tanh(Wh)*sigmoid(Mh)), Gt[n][k] = bf16(gate) ----
// tanh via 1 - 2/(exp(2x)+1): exact at +-inf, avoids branchy libm tanhf.
__global__ __launch_bounds__(256) void prep_wg(const float* __restrict__ Wh,
                                               const float* __restrict__ Mh,
                                               const float* __restrict__ Gf,
                                               ushort* __restrict__ Wt,
                                               ushort* __restrict__ Gt) {
    __shared__ float tw[32][33];
    __shared__ float tg[32][33];
    const int k0 = blockIdx.y * 32, n0 = blockIdx.x * 32;
    const int tx = threadIdx.x, ty = threadIdx.y;  // 32 x 8
#pragma unroll
    for (int i = 0; i < 4; i++) {
        int k = k0 + ty + i * 8;
        int n = n0 + tx;
        size_t idx = (size_t)k * N_DIM + n;
        float wh = Wh[idx], mh = Mh[idx];
        float e2 = __expf(2.f * wh);
        float th = 1.f - 2.f / (e2 + 1.f);          // tanh(wh)
        tw[ty + i * 8][tx] = th * (1.f / (1.f + __expf(-mh)));
        tg[ty + i * 8][tx] = Gf[idx];
    }
    __syncthreads();
#pragma unroll
    for (int i = 0; i < 4; i++) {
        int n = n0 + ty + i * 8;
        int k = k0 + tx;
        Wt[(size_t)n * K_DIM + k] = f2bf(tw[tx][ty + i * 8]);
        Gt[(size_t)n * K_DIM + k] = f2bf(tg[tx][ty + i * 8]);
    }
}

// ---------------- fused GEMM: a = Xb@Wt^T, lm = Lb@Wt^T, gl = Xb@Gt^T ----------------
// out = sigmoid(gl)*a + (1-sigmoid(gl))*exp(lm)
// 128x128 block tile, 4 waves (2x2), 64x64 per wave per acc set, BK=32.
//
// Round-3 change (single lever; round 2's 450us regression was __syncthreads'
// implicit "s_waitcnt vmcnt(0) lgkmcnt(0)" draining the just-issued stage
// loads with ZERO slack — counted vmcnt REQUIRES raw s_barrier):
//  * Raw __builtin_amdgcn_s_barrier() + explicit counted vmcnt(8). Main loop
//    never drains vmcnt(0); every wait targets loads issued one full compute
//    phase earlier. Compiler memory fences bracket each barrier so no LDS
//    read/write or gld_lds migrates across.
//    Hazards: WAR — each wave's ds_reads are consumed by MFMAs before its
//    barrier, so all reads complete before any wave's stage writes begin.
//    RAW — each wave waits vmcnt(8) for its OWN nxt loads, bar2 makes it
//    collective. Tail (h=62) drains vmcnt(0) with compute slack.
//  * Reverted round-2 T1 remap (FETCH unchanged 340->347MB: no gain) and T5
//    setprio (m190 null case on lockstep structure).
// Carried: T2 XOR bank-swizzle (rule #21: linear gld_lds dest, swizzle-inverse
// GLOBAL source, XOR on read address); LDS one object.
#define SEC  (128 * 32)        // elems per section (8 KB)
#define BUFE (4 * SEC)         // elems per buffer  (32 KB)

__global__ __launch_bounds__(256, 2) void gemm_fused(const ushort* __restrict__ Xb,
                                                     const ushort* __restrict__ Lb,
                                                     const ushort* __restrict__ Wt,
                                                     const ushort* __restrict__ Gt,
                                                     float* __restrict__ out) {
    __shared__ ushort smem[2 * BUFE];
    ushort* s0 = smem;
    ushort* s1 = smem + BUFE;

    const int t = threadIdx.x;
    const int lane = t & 63;
    const int w = t >> 6;
    const int wm = w >> 1, wn = w & 1;
    const int rowA = blockIdx.y * 128;   // M tile base
    const int rowB = blockIdx.x * 128;   // N tile base

    floatx4 acca[4][4], accm[4][4], accg[4][4];
    const floatx4 z = {0.f, 0.f, 0.f, 0.f};
#pragma unroll
    for (int i = 0; i < 4; i++)
#pragma unroll
        for (int j = 0; j < 4; j++) { acca[i][j] = z; accm[i][j] = z; accg[i][j] = z; }

    // ---- staging: swizzle-inverse source coordinates -------------------------
    // dest byte d (linear, = thread*16) holds global (r,c) with
    // d == (r*64 + c*16) ^ ((r&7)<<4).
    // inverse: r = 2*(d>>7) | ((d>>6)^(d>>8))&1 ; c = ((d>>4)&3) ^ (r&3).
    const int d0 = t * 16;
    const int d1 = (t + 256) * 16;
    const int r0 = ((d0 >> 7) << 1) | (((d0 >> 6) ^ (d0 >> 8)) & 1);
    const int c0 = ((d0 >> 4) & 3) ^ (r0 & 3);
    const int r1 = ((d1 >> 7) << 1) | (((d1 >> 6) ^ (d1 >> 8)) & 1);
    const int c1 = ((d1 >> 4) & 3) ^ (r1 & 3);
    const int ga0 = (rowA + r0) * K_DIM + c0 * 8;
    const int ga1 = (rowA + r1) * K_DIM + c1 * 8;
    const int gb0 = (rowB + r0) * K_DIM + c0 * 8;
    const int gb1 = (rowB + r1) * K_DIM + c1 * 8;
    const int e0 = t * 8, e1 = (t + 256) * 8;   // linear dest (elems)

#define STAGE(sb, k0) do {                                   \
    gld_lds16(Xb + ga0 + (k0), (sb) + e0);                   \
    gld_lds16(Xb + ga1 + (k0), (sb) + e1);                   \
    gld_lds16(Lb + ga0 + (k0), (sb) + SEC + e0);             \
    gld_lds16(Lb + ga1 + (k0), (sb) + SEC + e1);             \
    gld_lds16(Wt + gb0 + (k0), (sb) + 2 * SEC + e0);         \
    gld_lds16(Wt + gb1 + (k0), (sb) + 2 * SEC + e1);         \
    gld_lds16(Gt + gb0 + (k0), (sb) + 3 * SEC + e0);         \
    gld_lds16(Gt + gb1 + (k0), (sb) + 3 * SEC + e1);         \
} while (0)

    // ---- fragment read bases (byte offsets, swizzled) ------------------------
    const int lr = lane & 15;
    const int rbA = (((wm * 64 + lr) * 64) + ((lane >> 4) * 16)) ^ ((lr & 7) << 4);
    const int rbB = (((wn * 64 + lr) * 64) + ((lane >> 4) * 16)) ^ ((lr & 7) << 4);
    // per-mi/ni offsets are +mi*1024B (16 rows) — bits >=10, no swizzle overlap;
    // cross-section offset +SEC*2 bytes likewise.

#define COMPUTE(sb) do {                                                        \
    const char* bA = (const char*)(sb) + rbA;                                   \
    const char* bB = (const char*)(sb) + 2 * SEC * 2 + rbB;                     \
    short8 bw[4], bg[4];                                                        \
    _Pragma("unroll")                                                           \
    for (int ni = 0; ni < 4; ni++) {                                            \
        bw[ni] = *(const short8*)(bB + ni * 1024);                              \
        bg[ni] = *(const short8*)(bB + SEC * 2 + ni * 1024);                    \
    }                                                                           \
    _Pragma("unroll")                                                           \
    for (int mi = 0; mi < 4; mi++) {                                            \
        short8 ax = *(const short8*)(bA + mi * 1024);                           \
        short8 al = *(const short8*)(bA + SEC * 2 + mi * 1024);                 \
        _Pragma("unroll")                                                       \
        for (int ni = 0; ni < 4; ni++) {                                        \
            acca[mi][ni] = __builtin_amdgcn_mfma_f32_16x16x32_bf16(ax, bw[ni], acca[mi][ni], 0, 0, 0); \
            accm[mi][ni] = __builtin_amdgcn_mfma_f32_16x16x32_bf16(al, bw[ni], accm[mi][ni], 0, 0, 0); \
            accg[mi][ni] = __builtin_amdgcn_mfma_f32_16x16x32_bf16(ax, bg[ni], accg[mi][ni], 0, 0, 0); \
        }                                                                       \
    }                                                                           \
} while (0)

#define CFENCE() asm volatile("" ::: "memory")
#define BAR()    do { CFENCE(); __builtin_amdgcn_s_barrier(); CFENCE(); } while (0)
#define VMCNT8() asm volatile("s_waitcnt vmcnt(8)" ::: "memory")
#define VMCNT0() asm volatile("s_waitcnt vmcnt(0)" ::: "memory")

    // prologue: fill both buffers; wait only for s0 (s1's 8 stay in flight)
    STAGE(s0, 0);
    STAGE(s1, 32);
    VMCNT8();
    BAR();

#pragma unroll 1
    for (int h = 0; h < 64; h += 2) {
        const int k = h * 32;
        COMPUTE(s0);                    // s0 holds K-step h (k)
        BAR();                          // all waves done reading s0 (no drain)
        if (h < 62) {
            STAGE(s0, k + 64);          // in flight: s1's 8 + s0's new 8
            VMCNT8();                   // s1's loads landed (1 compute of slack)
        } else {
            VMCNT0();                   // h==62 tail: only s1's 8 in flight
        }
        BAR();                          // s1 collectively ready
        COMPUTE(s1);                    // s1 holds K-step h+1 (k+32)
        if (h < 62) {
            BAR();
            STAGE(s1, k + 96);          // h<=60 -> k+96 <= 2016, valid
            VMCNT8();                   // s0's loads landed
            BAR();
        }
    }

    const int rsub = (lane >> 4) << 2;
#pragma unroll
    for (int mi = 0; mi < 4; mi++)
#pragma unroll
        for (int ni = 0; ni < 4; ni++)
#pragma unroll
            for (int r = 0; r < 4; r++) {
                int row = rowA + wm * 64 + mi * 16 + rsub + r;
                int col = rowB + wn * 64 + ni * 16 + lr;
                float g = 1.f / (1.f + __expf(-accg[mi][ni][r]));
                float a = acca[mi][ni][r];
                float m = __expf(accm[mi][ni][r]);
                out[(size_t)row * N_DIM + col] = g * a + (1.f - g) * m;
            }
}

extern "C" void kernel_launch(void* const* d_in, const int* in_sizes, int n_in,
                              void* d_out, int out_size, void* d_ws, size_t ws_size,
                              hipStream_t stream) {
    const float* X  = (const float*)d_in[0];
    const float* Wh = (const float*)d_in[1];
    const float* Mh = (const float*)d_in[2];
    const float* Gf = (const float*)d_in[3];
    float* out = (float*)d_out;

    // workspace layout (bytes):
    //   Xb : B*K*2  = 33,554,432
    //   Lb : B*K*2  = 33,554,432
    //   Wt : N*K*2  =  8,388,608   (transposed: [n][k])
    //   Gt : N*K*2  =  8,388,608
    char* ws = (char*)d_ws;
    ushort* Xb = (ushort*)(ws);
    ushort* Lb = (ushort*)(ws + (size_t)B_DIM * K_DIM * 2);
    ushort* Wt = (ushort*)(ws + (size_t)B_DIM * K_DIM * 4);
    ushort* Gt = (ushort*)(ws + (size_t)B_DIM * K_DIM * 4 + (size_t)N_DIM * K_DIM * 2);

    prep_x<<<dim3((B_DIM * K_DIM) / (256 * 4)), dim3(256), 0, stream>>>(
        (const float4*)X, Xb, Lb);

    prep_wg<<<dim3(N_DIM / 32, K_DIM / 32), dim3(32, 8), 0, stream>>>(Wh, Mh, Gf, Wt, Gt);

    gemm_fused<<<dim3(N_DIM / 128, B_DIM / 128), dim3(256), 0, stream>>>(Xb, Lb, Wt, Gt, out);
}

// Round 5
// 401.050 us; speedup vs baseline: 1.4567x; 1.0569x over previous
//
#include <hip/hip_runtime.h>
#include <stdint.h>

typedef __attribute__((ext_vector_type(8))) short short8;
typedef __attribute__((ext_vector_type(4))) float floatx4;

#define B_DIM 8192
#define K_DIM 2048
#define N_DIM 2048

// round-to-nearest-even fp32 -> bf16
__device__ __forceinline__ unsigned short f2bf(float f) {
    union { float f; unsigned u; } v; v.f = f;
    unsigned r = v.u + 0x7fffu + ((v.u >> 16) & 1u);
    return (unsigned short)(r >> 16);
}

__device__ __forceinline__ void gld_lds16(const void* g, void* l) {
    __builtin_amdgcn_global_load_lds(
        (const __attribute__((address_space(1))) void*)g,
        (__attribute__((address_space(3))) void*)l, 16, 0, 0);
}

// ---------------- prepass 1: X -> Xb (bf16), Lb = bf16(log(|x|+eps)) ----------------
__global__ __launch_bounds__(256) void prep_x(const float4* __restrict__ X4,
                                              ushort* __restrict__ Xb,
                                              ushort* __restrict__ Lb) {
    int i = blockIdx.x * 256 + threadIdx.x;
    float4 v = X4[i];
    ushort4 xb, lb;
    xb.x = f2bf(v.x); xb.y = f2bf(v.y); xb.z = f2bf(v.z); xb.w = f2bf(v.w);
    lb.x = f2bf(__logf(fabsf(v.x) + 1e-7f));
    lb.y = f2bf(__logf(fabsf(v.y) + 1e-7f));
    lb.z = f2bf(__logf(fabsf(v.z) + 1e-7f));
    lb.w = f2bf(__logf(fabsf(v.w) + 1e-7f));
    *(ushort4*)(Xb + (size_t)i * 4) = xb;
    *(ushort4*)(Lb + (size_t)i * 4) = lb;
}

// ---------------- prepass 2: Wt[n][k] = bf16(tanh(Wh)*sigmoid(Mh)), Gt[n][k] = bf16(gate) ----
__global__ __launch_bounds__(256) void prep_wg(const float* __restrict__ Wh,
                                               const float* __restrict__ Mh,
                                               const float* __restrict__ Gf,
                                               ushort* __restrict__ Wt,
                                               ushort* __restrict__ Gt) {
    __shared__ float tw[32][33];
    __shared__ float tg[32][33];
    const int k0 = blockIdx.y * 32, n0 = blockIdx.x * 32;
    const int tx = threadIdx.x, ty = threadIdx.y;  // 32 x 8
#pragma unroll
    for (int i = 0; i < 4; i++) {
        int k = k0 + ty + i * 8;
        int n = n0 + tx;
        size_t idx = (size_t)k * N_DIM + n;
        float wh = Wh[idx], mh = Mh[idx];
        float e2 = __expf(2.f * wh);
        float th = 1.f - 2.f / (e2 + 1.f);          // tanh(wh)
        tw[ty + i * 8][tx] = th * (1.f / (1.f + __expf(-mh)));
        tg[ty + i * 8][tx] = Gf[idx];
    }
    __syncthreads();
#pragma unroll
    for (int i = 0; i < 4; i++) {
        int n = n0 + ty + i * 8;
        int k = k0 + tx;
        Wt[(size_t)n * K_DIM + k] = f2bf(tw[tx][ty + i * 8]);
        Gt[(size_t)n * K_DIM + k] = f2bf(tg[tx][ty + i * 8]);
    }
}

// ---------------- fused GEMM: a = Xb@Wt^T, lm = Lb@Wt^T, gl = Xb@Gt^T ----------------
// out = sigmoid(gl)*a + (1-sigmoid(gl))*exp(lm)
//
// Round-5 (= round-4 theory, compile-fixed): 4-phase quadrant interleave
// (m196/m201 mechanism). r1/r3 both 287us (coarse scheduling null, m196) —
// fix is the FINE interleave: each K-step split into 4 phases by acc quadrant
// {reads; barrier; lgkmcnt0+sched_barrier; setprio1; 12 MFMA; setprio0;
// barrier}. A wave ISSUES its MFMAs (~50cy) and runs ahead into the next
// phase's ds_reads while the matrix pipe drains; adjacent phases write
// DIFFERENT quadrants (no dep stall). Single counted vmcnt(12) per K-step;
// main loop never drains to 0.
//
// Geometry: BM=256, BN=128, BK=32, 8 waves (4Mx2N), wave tile 64x64. LDS
// 3 x 48KB rotating buffers (3-deep prefetch, ~2 K-steps vmcnt slack; needs
// hipFuncSetAttribute for 144KB dynamic LDS). Stage at PH3 targets CURRENT
// buffer (j+3 = j mod 3): all waves' reads of it retired at PH2's closing
// barrier (each wave's lgkmcnt(0) precedes its PH2 MFMAs; barrier makes it
// collective) -> WAR safe. RAW: vmcnt(12) at step j confirms buffer for step
// j+1. Carried: T2 XOR bank-swizzle (rule #21: linear gld_lds dest,
// swizzle-inverse GLOBAL source, XOR on read address).
// Ledger note: SQ_LDS_BANK_CONFLICT == 2^24 exactly in ALL rounds — treat as
// saturated/artifact, not a signal.
#define BUFE 24576            // elems per buffer (48 KB): X 8192 | L 8192 | W 4096 | G 4096

__global__ __launch_bounds__(512, 2) void gemm_fused(const ushort* __restrict__ Xb,
                                                     const ushort* __restrict__ Lb,
                                                     const ushort* __restrict__ Wt,
                                                     const ushort* __restrict__ Gt,
                                                     float* __restrict__ out) {
    extern __shared__ ushort smem[];

    const int t = threadIdx.x;          // 0..511
    const int lane = t & 63;
    const int w = t >> 6;               // 0..7
    const int wm = w >> 1;              // 0..3 (M quadrant of wave)
    const int wn = w & 1;               // 0..1 (N half)
    const int rowA = blockIdx.y * 256;  // M tile base
    const int rowB = blockIdx.x * 128;  // N tile base

    floatx4 acca[4][4], accm[4][4], accg[4][4];
    const floatx4 z = {0.f, 0.f, 0.f, 0.f};
#pragma unroll
    for (int i = 0; i < 4; i++)
#pragma unroll
        for (int j = 0; j < 4; j++) { acca[i][j] = z; accm[i][j] = z; accg[i][j] = z; }

    // ---- staging: swizzle-inverse source coordinates -------------------------
    // dest byte d holds global (r,c) with d == (r*64 + c*16) ^ ((r&7)<<4).
    // inverse: r = 2*(d>>7) | ((d>>6)^(d>>8))&1 ; c = ((d>>4)&3) ^ (r&3).
    const int d0 = t * 16;              // X/L round 0 (rows 0..127), W/G (rows 0..127)
    const int d1 = (t + 512) * 16;      // X/L round 1 (rows 128..255)
    const int sr0 = ((d0 >> 7) << 1) | (((d0 >> 6) ^ (d0 >> 8)) & 1);
    const int sc0 = ((d0 >> 4) & 3) ^ (sr0 & 3);
    const int sr1 = ((d1 >> 7) << 1) | (((d1 >> 6) ^ (d1 >> 8)) & 1);
    const int sc1 = ((d1 >> 4) & 3) ^ (sr1 & 3);
    const int ga0 = (rowA + sr0) * K_DIM + sc0 * 8;
    const int ga1 = (rowA + sr1) * K_DIM + sc1 * 8;
    const int gb0 = (rowB + sr0) * K_DIM + sc0 * 8;
    const int e0 = t * 8, e1 = (t + 512) * 8;   // linear dest (elems)

#define STAGE(sb, kk) do {                                   \
    gld_lds16(Xb + ga0 + (kk), (sb) + e0);                   \
    gld_lds16(Xb + ga1 + (kk), (sb) + e1);                   \
    gld_lds16(Lb + ga0 + (kk), (sb) + 8192 + e0);            \
    gld_lds16(Lb + ga1 + (kk), (sb) + 8192 + e1);            \
    gld_lds16(Wt + gb0 + (kk), (sb) + 16384 + e0);           \
    gld_lds16(Gt + gb0 + (kk), (sb) + 20480 + e0);           \
} while (0)

    // ---- fragment read bases (byte offsets, swizzled) ------------------------
    const int lr = lane & 15;
    const int ck = lane >> 4;
    const int rbA = (((wm * 64 + lr) * 64) + ck * 16) ^ ((lr & 7) << 4);
    const int rbB = (((wn * 64 + lr) * 64) + ck * 16) ^ ((lr & 7) << 4);
    // per-mi/ni offsets +1024B (16 rows) live in bits >=10: no swizzle overlap.

#define TRIP(MI, NI, AX, AL, BW, BG)                                                        \
    acca[MI][NI] = __builtin_amdgcn_mfma_f32_16x16x32_bf16(AX, BW, acca[MI][NI], 0, 0, 0);  \
    accm[MI][NI] = __builtin_amdgcn_mfma_f32_16x16x32_bf16(AL, BW, accm[MI][NI], 0, 0, 0);  \
    accg[MI][NI] = __builtin_amdgcn_mfma_f32_16x16x32_bf16(AX, BG, accg[MI][NI], 0, 0, 0);

#define CF()    asm volatile("" ::: "memory")
#define BAR()   do { CF(); __builtin_amdgcn_s_barrier(); CF(); } while (0)
#define LGKM0() do { asm volatile("s_waitcnt lgkmcnt(0)" ::: "memory"); \
                     __builtin_amdgcn_sched_barrier(0); } while (0)
#define PRIO1() __builtin_amdgcn_s_setprio(1)
#define PRIO0() __builtin_amdgcn_s_setprio(0)
#define VM12()  asm volatile("s_waitcnt vmcnt(12)" ::: "memory")
#define VM6()   asm volatile("s_waitcnt vmcnt(6)" ::: "memory")
#define VM0()   asm volatile("s_waitcnt vmcnt(0)" ::: "memory")

    // One K-step = 4 phases by acc quadrant. STG runs after PH2's closing
    // barrier (all reads of CUR retired). VMW releases the buffer read next.
#define STEP(CUR, STG, VMW) do {                                           \
    const char* bA  = (const char*)(CUR) + rbA;                            \
    const char* bAl = (const char*)(CUR) + 16384 + rbA;                    \
    const char* bB  = (const char*)(CUR) + 32768 + rbB;                    \
    const char* bBg = (const char*)(CUR) + 40960 + rbB;                    \
    /* PH0: 8 reads, MFMA quadrant (mi 0-1, ni 0-1) */                     \
    short8 ax0 = *(const short8*)(bA);                                     \
    short8 ax1 = *(const short8*)(bA + 1024);                              \
    short8 al0 = *(const short8*)(bAl);                                    \
    short8 al1 = *(const short8*)(bAl + 1024);                             \
    short8 bw0 = *(const short8*)(bB);                                     \
    short8 bw1 = *(const short8*)(bB + 1024);                              \
    short8 bg0 = *(const short8*)(bBg);                                    \
    short8 bg1 = *(const short8*)(bBg + 1024);                             \
    BAR(); LGKM0(); PRIO1();                                               \
    TRIP(0,0,ax0,al0,bw0,bg0) TRIP(0,1,ax0,al0,bw1,bg1)                    \
    TRIP(1,0,ax1,al1,bw0,bg0) TRIP(1,1,ax1,al1,bw1,bg1)                    \
    PRIO0(); BAR();                                                        \
    /* PH1: 4 reads, quadrant (mi 0-1, ni 2-3) */                          \
    short8 bw2 = *(const short8*)(bB + 2048);                              \
    short8 bw3 = *(const short8*)(bB + 3072);                              \
    short8 bg2 = *(const short8*)(bBg + 2048);                             \
    short8 bg3 = *(const short8*)(bBg + 3072);                             \
    BAR(); LGKM0(); PRIO1();                                               \
    TRIP(0,2,ax0,al0,bw2,bg2) TRIP(0,3,ax0,al0,bw3,bg3)                    \
    TRIP(1,2,ax1,al1,bw2,bg2) TRIP(1,3,ax1,al1,bw3,bg3)                    \
    PRIO0(); BAR();                                                        \
    /* PH2: 4 reads, quadrant (mi 2-3, ni 0-1) */                          \
    short8 ax2 = *(const short8*)(bA + 2048);                              \
    short8 ax3 = *(const short8*)(bA + 3072);                              \
    short8 al2 = *(const short8*)(bAl + 2048);                             \
    short8 al3 = *(const short8*)(bAl + 3072);                             \
    BAR(); LGKM0(); PRIO1();                                               \
    TRIP(2,0,ax2,al2,bw0,bg0) TRIP(2,1,ax2,al2,bw1,bg1)                    \
    TRIP(3,0,ax3,al3,bw0,bg0) TRIP(3,1,ax3,al3,bw1,bg1)                    \
    PRIO0(); BAR();                                                        \
    /* PH3: stage (WAR-safe here), quadrant (mi 2-3, ni 2-3), counted vm */ \
    STG;                                                                   \
    BAR(); PRIO1();                                                        \
    TRIP(2,2,ax2,al2,bw2,bg2) TRIP(2,3,ax2,al2,bw3,bg3)                    \
    TRIP(3,2,ax3,al3,bw2,bg2) TRIP(3,3,ax3,al3,bw3,bg3)                    \
    PRIO0(); VMW; BAR();                                                   \
} while (0)

    ushort* pb0 = smem;
    ushort* pb1 = smem + BUFE;
    ushort* pb2 = smem + 2 * BUFE;

    // prologue: fill 3 buffers (18 loads in flight), wait only for buffer 0
    STAGE(pb0, 0);
    STAGE(pb1, 32);
    STAGE(pb2, 64);
    VM12();
    BAR();

    // steady state: j=0..60 stage K-step j+3 into CUR; tails j=61..63 drain
#pragma unroll 1
    for (int j = 0; j <= 60; ++j) {
        const int kst = (j + 3) * 32;
        STEP(pb0, STAGE(pb0, kst), VM12());
        ushort* tmp = pb0; pb0 = pb1; pb1 = pb2; pb2 = tmp;
    }
    STEP(pb0, ((void)0), VM6());
    { ushort* tmp = pb0; pb0 = pb1; pb1 = pb2; pb2 = tmp; }
    STEP(pb0, ((void)0), VM0());
    { ushort* tmp = pb0; pb0 = pb1; pb1 = pb2; pb2 = tmp; }
    STEP(pb0, ((void)0), ((void)0));

    // ---- epilogue -----------------------------------------------------------
    const int rsub = ck << 2;
#pragma unroll
    for (int mi = 0; mi < 4; mi++)
#pragma unroll
        for (int ni = 0; ni < 4; ni++)
#pragma unroll
            for (int r = 0; r < 4; r++) {
                int row = rowA + wm * 64 + mi * 16 + rsub + r;
                int col = rowB + wn * 64 + ni * 16 + lr;
                float g = 1.f / (1.f + __expf(-accg[mi][ni][r]));
                float a = acca[mi][ni][r];
                float m = __expf(accm[mi][ni][r]);
                out[(size_t)row * N_DIM + col] = g * a + (1.f - g) * m;
            }
}

extern "C" void kernel_launch(void* const* d_in, const int* in_sizes, int n_in,
                              void* d_out, int out_size, void* d_ws, size_t ws_size,
                              hipStream_t stream) {
    const float* X  = (const float*)d_in[0];
    const float* Wh = (const float*)d_in[1];
    const float* Mh = (const float*)d_in[2];
    const float* Gf = (const float*)d_in[3];
    float* out = (float*)d_out;

    // workspace layout (bytes):
    //   Xb : B*K*2  = 33,554,432
    //   Lb : B*K*2  = 33,554,432
    //   Wt : N*K*2  =  8,388,608   (transposed: [n][k])
    //   Gt : N*K*2  =  8,388,608
    char* ws = (char*)d_ws;
    ushort* Xb = (ushort*)(ws);
    ushort* Lb = (ushort*)(ws + (size_t)B_DIM * K_DIM * 2);
    ushort* Wt = (ushort*)(ws + (size_t)B_DIM * K_DIM * 4);
    ushort* Gt = (ushort*)(ws + (size_t)B_DIM * K_DIM * 4 + (size_t)N_DIM * K_DIM * 2);

    // 144KB dynamic LDS exceeds the default per-block cap — raise it once.
    static bool attr_set = false;
    if (!attr_set) {
        hipFuncSetAttribute((const void*)gemm_fused,
                            hipFuncAttributeMaxDynamicSharedMemorySize,
                            3 * BUFE * 2);
        attr_set = true;
    }

    prep_x<<<dim3((B_DIM * K_DIM) / (256 * 4)), dim3(256), 0, stream>>>(
        (const float4*)X, Xb, Lb);

    prep_wg<<<dim3(N_DIM / 32, K_DIM / 32), dim3(32, 8), 0, stream>>>(Wh, Mh, Gf, Wt, Gt);

    // 3 buffers x 48KB = 144KB dynamic LDS
    gemm_fused<<<dim3(N_DIM / 128, B_DIM / 256), dim3(512), 3 * BUFE * 2, stream>>>(
        Xb, Lb, Wt, Gt, out);
}